// Round 1
// baseline (853.347 us; speedup 1.0000x reference)
//
#include <hip/hip_runtime.h>

#define D 128
#define TM 64
#define TN 64

// ---------------- degree count ----------------
__global__ __launch_bounds__(256) void k_count(const int* __restrict__ dst, int* __restrict__ cnt, int E) {
  int stride = gridDim.x * blockDim.x;
  for (int i = blockIdx.x * blockDim.x + threadIdx.x; i < E; i += stride)
    atomicAdd(&cnt[dst[i]], 1);
}

// ---------------- single-block exclusive scan over cnt -> rowstart, cursor ----------------
__global__ __launch_bounds__(1024) void k_scan(const int* __restrict__ cnt, int* __restrict__ rowstart,
                                               int* __restrict__ cursor, int n) {
  __shared__ int lds[1024];
  __shared__ int carry_s;
  int t = threadIdx.x;
  if (t == 0) carry_s = 0;
  __syncthreads();
  int nchunks = (n + 1023) >> 10;
  for (int cc = 0; cc < nchunks; ++cc) {
    int i = (cc << 10) + t;
    int v = (i < n) ? cnt[i] : 0;
    lds[t] = v;
    __syncthreads();
    for (int off = 1; off < 1024; off <<= 1) {
      int x = (t >= off) ? lds[t - off] : 0;
      __syncthreads();
      lds[t] += x;
      __syncthreads();
    }
    int incl = lds[t];
    int base = carry_s;                 // read before the barrier that precedes the update
    if (i < n) { int rs = base + incl - v; rowstart[i] = rs; cursor[i] = rs; }
    __syncthreads();
    if (t == 1023) carry_s = base + lds[1023];
    __syncthreads();
  }
  if (t == 0) rowstart[n] = carry_s;
}

// ---------------- dinv = rsqrt(deg+1) ----------------
__global__ __launch_bounds__(256) void k_dinv(const int* __restrict__ cnt, float* __restrict__ dinv, int n) {
  int stride = gridDim.x * blockDim.x;
  for (int i = blockIdx.x * blockDim.x + threadIdx.x; i < n; i += stride)
    dinv[i] = rsqrtf((float)cnt[i] + 1.0f);
}

// ---------------- CSR fill ----------------
__global__ __launch_bounds__(256) void k_fill(const int* __restrict__ src, const int* __restrict__ dst,
                                              int* __restrict__ cursor, int* __restrict__ csr, int E) {
  int stride = gridDim.x * blockDim.x;
  for (int i = blockIdx.x * blockDim.x + threadIdx.x; i < E; i += stride) {
    int p = atomicAdd(&cursor[dst[i]], 1);
    csr[p] = src[i];
  }
}

// ---------------- f32 tiled GEMM: C[M,ncols] = A[M,128] @ W[128,ncols] (+bias) (+C) ----------------
template<bool BIAS, bool ACCUM>
__global__ __launch_bounds__(256) void k_gemm(const float* __restrict__ A, const float* __restrict__ W,
                                              const float* __restrict__ bias, float* __restrict__ C,
                                              int M, int ncols) {
  __shared__ float At[D][TM];   // [k][row] 32KB
  __shared__ float Ws[D][TN];   // [k][col] 32KB
  int row0 = blockIdx.x * TM;
  int col0 = blockIdx.y * TN;
  int tid = threadIdx.x;

  // load A tile (transposed into LDS)
  {
    int r = tid >> 2;
    int row = row0 + r;
    bool valid = (row < M);
    const float* Ap = A + (size_t)row * D;
    #pragma unroll
    for (int j = 0; j < 8; ++j) {
      int k4 = (tid & 3) + j * 4;
      float4 v = valid ? *(const float4*)(Ap + k4 * 4) : make_float4(0.f, 0.f, 0.f, 0.f);
      int k = k4 * 4;
      At[k][r] = v.x; At[k + 1][r] = v.y; At[k + 2][r] = v.z; At[k + 3][r] = v.w;
    }
  }
  // load W tile
  {
    #pragma unroll
    for (int j = 0; j < 8; ++j) {
      int k = (tid >> 4) + j * 16;
      int c = (tid & 15) * 4;
      float4 v = *(const float4*)(W + (size_t)k * ncols + col0 + c);
      *(float4*)&Ws[k][c] = v;
    }
  }
  __syncthreads();

  int tx = tid & 15, ty = tid >> 4;
  float acc[4][4] = {};
  #pragma unroll 8
  for (int k = 0; k < D; ++k) {
    float4 a = *(const float4*)&At[k][ty * 4];
    float4 w = *(const float4*)&Ws[k][tx * 4];
    float av[4] = {a.x, a.y, a.z, a.w};
    float wv[4] = {w.x, w.y, w.z, w.w};
    #pragma unroll
    for (int r = 0; r < 4; ++r)
      #pragma unroll
      for (int c = 0; c < 4; ++c)
        acc[r][c] += av[r] * wv[c];
  }

  float4 bv = make_float4(0.f, 0.f, 0.f, 0.f);
  if (BIAS) bv = *(const float4*)&bias[col0 + tx * 4];
  #pragma unroll
  for (int r = 0; r < 4; ++r) {
    int row = row0 + ty * 4 + r;
    if (row < M) {
      float4* cp = (float4*)&C[(size_t)row * ncols + col0 + tx * 4];
      float4 o;
      o.x = acc[r][0] + bv.x; o.y = acc[r][1] + bv.y;
      o.z = acc[r][2] + bv.z; o.w = acc[r][3] + bv.w;
      if (ACCUM) { float4 old = *cp; o.x += old.x; o.y += old.y; o.z += old.z; o.w += old.w; }
      *cp = o;
    }
  }
}

// ---------------- aggregation: one wave per dst node; pre written in-place over hl ----------------
__global__ __launch_bounds__(256) void k_agg(const float* __restrict__ hg, float* __restrict__ pre,
                                             const int* __restrict__ rowstart, const int* __restrict__ csr,
                                             const float* __restrict__ dinv,
                                             const float* __restrict__ bg, const float* __restrict__ bl, int n) {
  int node = (int)((blockIdx.x * blockDim.x + threadIdx.x) >> 6);
  if (node >= n) return;
  int lane = threadIdx.x & 63;
  int s = rowstart[node], e = rowstart[node + 1];
  float acc0 = 0.f, acc1 = 0.f;
  for (int j = s; j < e; ++j) {
    int sn = csr[j];
    float w = dinv[sn];
    const float* hp = hg + (size_t)sn * D;
    acc0 += w * hp[lane];
    acc1 += w * hp[lane + 64];
  }
  float dn = dinv[node];
  float selfn = dn * dn;
  const float* hgp = hg + (size_t)node * D;
  float* pp = pre + (size_t)node * D;
  float p0 = dn * acc0 + hgp[lane] * selfn + bg[lane] + pp[lane] + bl[lane];
  float p1 = dn * acc1 + hgp[lane + 64] * selfn + bg[lane + 64] + pp[lane + 64] + bl[lane + 64];
  pp[lane] = p0;
  pp[lane + 64] = p1;
}

// ---------------- BN batch stats: partial sums + atomics ----------------
__global__ __launch_bounds__(256) void k_stats(const float* __restrict__ pre, float* __restrict__ stats, int n) {
  const int ROWS = 512;
  int c = threadIdx.x & 127;
  int half = threadIdx.x >> 7;
  int r0 = blockIdx.x * ROWS;
  int r1 = min(n, r0 + ROWS);
  float s = 0.f, q = 0.f;
  for (int r = r0 + half; r < r1; r += 2) {
    float v = pre[(size_t)r * D + c];
    s += v; q += v * v;
  }
  __shared__ float ls[256], lq[256];
  ls[threadIdx.x] = s; lq[threadIdx.x] = q;
  __syncthreads();
  if (threadIdx.x < 128) {
    s = ls[threadIdx.x] + ls[threadIdx.x + 128];
    q = lq[threadIdx.x] + lq[threadIdx.x + 128];
    atomicAdd(&stats[c], s);
    atomicAdd(&stats[128 + c], q);
  }
}

// ---------------- BN finalize: a = gamma*inv, b = beta - mean*inv*gamma ----------------
__global__ void k_finalize(const float* __restrict__ stats, const float* __restrict__ gamma,
                           const float* __restrict__ beta, float* __restrict__ ab, float invN) {
  int c = threadIdx.x;  // 128 threads
  float mean = stats[c] * invN;
  float var = stats[128 + c] * invN - mean * mean;
  float inv = rsqrtf(var + 1e-5f);
  float g = gamma[c];
  ab[c] = g * inv;
  ab[128 + c] = beta[c] - mean * inv * g;
}

// ---------------- normalize + relu -> h ----------------
__global__ __launch_bounds__(256) void k_norm(const float* __restrict__ pre, const float* __restrict__ ab,
                                              float* __restrict__ h, int total4) {
  int stride = gridDim.x * blockDim.x;
  for (int idx = blockIdx.x * blockDim.x + threadIdx.x; idx < total4; idx += stride) {
    int c4 = idx & 31;  // 32 float4 per 128-channel row
    float4 p = ((const float4*)pre)[idx];
    float4 a = ((const float4*)ab)[c4];
    float4 b = ((const float4*)(ab + 128))[c4];
    float4 o;
    o.x = fmaxf(p.x * a.x + b.x, 0.f);
    o.y = fmaxf(p.y * a.y + b.y, 0.f);
    o.z = fmaxf(p.z * a.z + b.z, 0.f);
    o.w = fmaxf(p.w * a.w + b.w, 0.f);
    ((float4*)h)[idx] = o;
  }
}

extern "C" void kernel_launch(void* const* d_in, const int* in_sizes, int n_in,
                              void* d_out, int out_size, void* d_ws, size_t ws_size,
                              hipStream_t stream) {
  const float* x     = (const float*)d_in[0];
  const int*   ei    = (const int*)d_in[1];
  const float* Wg    = (const float*)d_in[2];
  const float* bg    = (const float*)d_in[3];
  const float* Wl    = (const float*)d_in[4];
  const float* bl    = (const float*)d_in[5];
  const float* gamma = (const float*)d_in[6];
  const float* beta  = (const float*)d_in[7];
  const float* Wp    = (const float*)d_in[8];
  const float* bp    = (const float*)d_in[9];
  float* out = (float*)d_out;

  int N = in_sizes[0] / D;
  int E = in_sizes[1] / 2;
  int OUT = in_sizes[9];
  const int* srcp = ei;
  const int* dstp = ei + E;

  char* wsb = (char*)d_ws;
  size_t off = 0;
  auto alloc = [&](size_t bytes) {
    off = (off + 255) & ~(size_t)255;
    void* p = wsb + off;
    off += bytes;
    return p;
  };
  float* dinv     = (float*)alloc((size_t)N * 4);
  int*   cnt      = (int*)alloc((size_t)N * 4);
  int*   rowstart = (int*)alloc((size_t)(N + 1) * 4);
  int*   cursor   = (int*)alloc((size_t)N * 4);
  int*   csr      = (int*)alloc((size_t)E * 4);
  float* stats    = (float*)alloc(3 * 256 * 4);
  float* ab       = (float*)alloc(3 * 256 * 4);
  float* hg       = (float*)alloc((size_t)N * D * 4);
  float* hl       = (float*)alloc((size_t)N * D * 4);
  float* h        = (float*)alloc((size_t)N * D * 4);
  (void)ws_size; (void)n_in; (void)out_size;

  hipMemsetAsync(cnt, 0, (size_t)N * 4, stream);
  hipMemsetAsync(stats, 0, 3 * 256 * 4, stream);

  k_count<<<512, 256, 0, stream>>>(dstp, cnt, E);
  k_scan<<<1, 1024, 0, stream>>>(cnt, rowstart, cursor, N);
  k_dinv<<<(N + 255) / 256, 256, 0, stream>>>(cnt, dinv, N);
  k_fill<<<512, 256, 0, stream>>>(srcp, dstp, cursor, csr, E);

  int mt = (N + TM - 1) / TM;
  for (int i = 0; i < 3; ++i) {
    const float* A = (i == 0) ? x : h;
    k_gemm<false, false><<<dim3(mt, D / TN), 256, 0, stream>>>(A, Wg + (size_t)i * D * D, nullptr, hg, N, D);
    k_gemm<false, false><<<dim3(mt, D / TN), 256, 0, stream>>>(A, Wl + (size_t)i * D * D, nullptr, hl, N, D);
    k_agg<<<(N + 3) / 4, 256, 0, stream>>>(hg, hl, rowstart, csr, dinv, bg + (size_t)i * D, bl + (size_t)i * D, N);
    k_stats<<<(N + 511) / 512, 256, 0, stream>>>(hl, stats + i * 256, N);
    k_finalize<<<1, 128, 0, stream>>>(stats + i * 256, gamma + (size_t)i * D, beta + (size_t)i * D, ab + i * 256, 1.0f / (float)N);
    k_norm<<<1024, 256, 0, stream>>>(hl, ab + i * 256, h, N * (D / 4));
    if (i == 0) k_gemm<true,  false><<<dim3(mt, 1), 256, 0, stream>>>(h, Wp, bp, out, N, OUT);
    else        k_gemm<false, true ><<<dim3(mt, 1), 256, 0, stream>>>(h, Wp, nullptr, out, N, OUT);
  }
}

// Round 2
// 712.440 us; speedup vs baseline: 1.1978x; 1.1978x over previous
//
#include <hip/hip_runtime.h>

#define D 128
#define OUTC 64
#define TM 64

// ---------- helpers ----------
__device__ inline unsigned short f2bf(float f) {
  unsigned int u = __float_as_uint(f);
  unsigned int r = (u + 0x7FFF + ((u >> 16) & 1)) >> 16;  // RNE
  return (unsigned short)r;
}

// ---------------- degree count ----------------
__global__ __launch_bounds__(256) void k_count(const int* __restrict__ dst, int* __restrict__ cnt, int E) {
  int stride = gridDim.x * blockDim.x;
  for (int i = blockIdx.x * blockDim.x + threadIdx.x; i < E; i += stride)
    atomicAdd(&cnt[dst[i]], 1);
}

// ---------------- hierarchical scan ----------------
// block-level scan helper: 256 threads, 4 elems/thread; returns exclusive prefix
// of this thread's 4-sum; *total = block total.
__device__ inline int block_scan4(int4 v, int t, int* total) {
  int s = v.x + v.y + v.z + v.w;
  int lane = t & 63, w = t >> 6;
  int incl = s;
  #pragma unroll
  for (int off = 1; off < 64; off <<= 1) {
    int nb = __shfl_up(incl, off);
    if (lane >= off) incl += nb;
  }
  __shared__ int wsum[4];
  if (lane == 63) wsum[w] = incl;
  __syncthreads();
  int woff = 0;
  #pragma unroll
  for (int k = 0; k < 3; ++k) if (w > k) woff += wsum[k];
  if (total) *total = wsum[0] + wsum[1] + wsum[2] + wsum[3];
  return woff + incl - s;
}

// s1: per-1024-chunk local exclusive scan, emit block sums
__global__ __launch_bounds__(256) void k_scan1(const int* __restrict__ cnt, int* __restrict__ lpre,
                                               int* __restrict__ bsum, int n) {
  int t = threadIdx.x;
  int i0 = blockIdx.x * 1024 + t * 4;
  int4 v = make_int4(0, 0, 0, 0);
  if (i0 + 3 < n) v = *(const int4*)(cnt + i0);
  else {
    if (i0 < n) v.x = cnt[i0];
    if (i0 + 1 < n) v.y = cnt[i0 + 1];
    if (i0 + 2 < n) v.z = cnt[i0 + 2];
    if (i0 + 3 < n) v.w = cnt[i0 + 3];
  }
  int total;
  int e = block_scan4(v, t, &total);
  if (i0 < n) {
    int4 o;
    o.x = e; o.y = e + v.x; o.z = o.y + v.y; o.w = o.z + v.z;
    if (i0 + 3 < n) *(int4*)(lpre + i0) = o;
    else {
      lpre[i0] = o.x;
      if (i0 + 1 < n) lpre[i0 + 1] = o.y;
      if (i0 + 2 < n) lpre[i0 + 2] = o.z;
    }
  }
  if (t == 0) bsum[blockIdx.x] = total;
}

// s2: exclusive scan of block sums in place (nb <= 1024)
__global__ __launch_bounds__(256) void k_scan2(int* __restrict__ bsum, int nb) {
  int t = threadIdx.x;
  int i0 = t * 4;
  int4 v = make_int4(0, 0, 0, 0);
  if (i0 + 3 < nb) v = *(const int4*)(bsum + i0);
  else {
    if (i0 < nb) v.x = bsum[i0];
    if (i0 + 1 < nb) v.y = bsum[i0 + 1];
    if (i0 + 2 < nb) v.z = bsum[i0 + 2];
    if (i0 + 3 < nb) v.w = bsum[i0 + 3];
  }
  int e = block_scan4(v, t, nullptr);
  if (i0 < nb) {
    bsum[i0] = e;
    if (i0 + 1 < nb) bsum[i0 + 1] = e + v.x;
    if (i0 + 2 < nb) bsum[i0 + 2] = e + v.x + v.y;
    if (i0 + 3 < nb) bsum[i0 + 3] = e + v.x + v.y + v.z;
  }
}

// s3: add block offsets, emit rowstart+cursor+dinv, set rowstart[n]=E
__global__ __launch_bounds__(256) void k_scan3(int* __restrict__ rowstart, const int* __restrict__ bsum,
                                               int* __restrict__ cursor, const int* __restrict__ cnt,
                                               float* __restrict__ dinv, int n, int E) {
  int i = blockIdx.x * 256 + threadIdx.x;
  if (i < n) {
    int r = rowstart[i] + bsum[i >> 10];
    rowstart[i] = r;
    cursor[i] = r;
    dinv[i] = rsqrtf((float)cnt[i] + 1.0f);
  }
  if (i == 0) rowstart[n] = E;
}

// ---------------- CSR fill ----------------
__global__ __launch_bounds__(256) void k_fill(const int* __restrict__ src, const int* __restrict__ dst,
                                              int* __restrict__ cursor, int* __restrict__ csr, int E) {
  int stride = gridDim.x * blockDim.x;
  for (int i = blockIdx.x * blockDim.x + threadIdx.x; i < E; i += stride) {
    int p = atomicAdd(&cursor[dst[i]], 1);
    csr[p] = src[i];
  }
}

// ---------------- dual GEMM: hg(bf16) = A@Wg, hl(f32) = A@Wl, shared A-tile ----------------
__global__ __launch_bounds__(256) void k_dual(const float* __restrict__ A, const float* __restrict__ Wg,
                                              const float* __restrict__ Wl,
                                              unsigned short* __restrict__ hg, float* __restrict__ hl, int M) {
  __shared__ float At[D][TM];   // [k][row] 32KB
  __shared__ float Ws[D][64];   // 32KB (reused for Wg then Wl)
  int row0 = blockIdx.x * TM;
  int col0 = blockIdx.y * 64;
  int tid = threadIdx.x;

  // A tile (transposed)
  {
    int r = tid >> 2;
    int row = row0 + r;
    bool valid = (row < M);
    const float* Ap = A + (size_t)row * D;
    #pragma unroll
    for (int j = 0; j < 8; ++j) {
      int k4 = (tid & 3) + j * 4;
      float4 v = valid ? *(const float4*)(Ap + k4 * 4) : make_float4(0.f, 0.f, 0.f, 0.f);
      int k = k4 * 4;
      At[k][r] = v.x; At[k + 1][r] = v.y; At[k + 2][r] = v.z; At[k + 3][r] = v.w;
    }
  }
  // Wg tile
  {
    #pragma unroll
    for (int j = 0; j < 8; ++j) {
      int k = (tid >> 4) + j * 16;
      int c = (tid & 15) * 4;
      *(float4*)&Ws[k][c] = *(const float4*)(Wg + (size_t)k * D + col0 + c);
    }
  }
  __syncthreads();

  int tx = tid & 15, ty = tid >> 4;
  float accg[4][4] = {};
  #pragma unroll 8
  for (int k = 0; k < D; ++k) {
    float4 a = *(const float4*)&At[k][ty * 4];
    float4 w = *(const float4*)&Ws[k][tx * 4];
    float av[4] = {a.x, a.y, a.z, a.w};
    float wv[4] = {w.x, w.y, w.z, w.w};
    #pragma unroll
    for (int r = 0; r < 4; ++r)
      #pragma unroll
      for (int c = 0; c < 4; ++c)
        accg[r][c] += av[r] * wv[c];
  }
  // write hg (bf16)
  #pragma unroll
  for (int r = 0; r < 4; ++r) {
    int row = row0 + ty * 4 + r;
    if (row < M) {
      ushort4 o;
      o.x = f2bf(accg[r][0]); o.y = f2bf(accg[r][1]);
      o.z = f2bf(accg[r][2]); o.w = f2bf(accg[r][3]);
      *(ushort4*)&hg[(size_t)row * D + col0 + tx * 4] = o;
    }
  }
  __syncthreads();
  // Wl tile
  {
    #pragma unroll
    for (int j = 0; j < 8; ++j) {
      int k = (tid >> 4) + j * 16;
      int c = (tid & 15) * 4;
      *(float4*)&Ws[k][c] = *(const float4*)(Wl + (size_t)k * D + col0 + c);
    }
  }
  __syncthreads();
  float accl[4][4] = {};
  #pragma unroll 8
  for (int k = 0; k < D; ++k) {
    float4 a = *(const float4*)&At[k][ty * 4];
    float4 w = *(const float4*)&Ws[k][tx * 4];
    float av[4] = {a.x, a.y, a.z, a.w};
    float wv[4] = {w.x, w.y, w.z, w.w};
    #pragma unroll
    for (int r = 0; r < 4; ++r)
      #pragma unroll
      for (int c = 0; c < 4; ++c)
        accl[r][c] += av[r] * wv[c];
  }
  #pragma unroll
  for (int r = 0; r < 4; ++r) {
    int row = row0 + ty * 4 + r;
    if (row < M) {
      float4 o;
      o.x = accl[r][0]; o.y = accl[r][1]; o.z = accl[r][2]; o.w = accl[r][3];
      *(float4*)&hl[(size_t)row * D + col0 + tx * 4] = o;
    }
  }
}

// ---------------- aggregation: one wave per dst node; hg bf16, pre in-place over hl ----------------
__global__ __launch_bounds__(256) void k_agg(const unsigned short* __restrict__ hg, float* __restrict__ pre,
                                             const int* __restrict__ rowstart, const int* __restrict__ csr,
                                             const float* __restrict__ dinv,
                                             const float* __restrict__ bg, const float* __restrict__ bl, int n) {
  int node = (int)((blockIdx.x * blockDim.x + threadIdx.x) >> 6);
  if (node >= n) return;
  int lane = threadIdx.x & 63;
  int s = rowstart[node], e = rowstart[node + 1];
  const unsigned int* base = (const unsigned int*)hg;  // 2 bf16 per dword
  float a0 = 0.f, a1 = 0.f;
  for (int j = s; j < e; ++j) {
    int sn = csr[j];
    float w = dinv[sn];
    unsigned int p = base[(size_t)sn * 64 + lane];
    a0 += w * __uint_as_float(p << 16);
    a1 += w * __uint_as_float(p & 0xFFFF0000u);
  }
  float dn = dinv[node];
  float sf = dn * dn;
  unsigned int ps = base[(size_t)node * 64 + lane];
  float h0 = __uint_as_float(ps << 16);
  float h1 = __uint_as_float(ps & 0xFFFF0000u);
  int c = lane * 2;
  float* pp = pre + (size_t)node * D;
  float2 old = *(const float2*)(pp + c);
  float p0 = dn * a0 + h0 * sf + bg[c] + old.x + bl[c];
  float p1 = dn * a1 + h1 * sf + bg[c + 1] + old.y + bl[c + 1];
  *(float2*)(pp + c) = make_float2(p0, p1);
}

// ---------------- BN batch stats ----------------
__global__ __launch_bounds__(256) void k_stats(const float* __restrict__ pre, float* __restrict__ stats, int n) {
  const int ROWS = 512;
  int c = threadIdx.x & 127;
  int half = threadIdx.x >> 7;
  int r0 = blockIdx.x * ROWS;
  int r1 = min(n, r0 + ROWS);
  float s = 0.f, q = 0.f;
  for (int r = r0 + half; r < r1; r += 2) {
    float v = pre[(size_t)r * D + c];
    s += v; q += v * v;
  }
  __shared__ float ls[256], lq[256];
  ls[threadIdx.x] = s; lq[threadIdx.x] = q;
  __syncthreads();
  if (threadIdx.x < 128) {
    s = ls[threadIdx.x] + ls[threadIdx.x + 128];
    q = lq[threadIdx.x] + lq[threadIdx.x + 128];
    atomicAdd(&stats[c], s);
    atomicAdd(&stats[128 + c], q);
  }
}

// ---------------- BN finalize ----------------
__global__ void k_finalize(const float* __restrict__ stats, const float* __restrict__ gamma,
                           const float* __restrict__ beta, float* __restrict__ ab, float invN) {
  int c = threadIdx.x;  // 128 threads
  float mean = stats[c] * invN;
  float var = stats[128 + c] * invN - mean * mean;
  float inv = rsqrtf(var + 1e-5f);
  float g = gamma[c];
  ab[c] = g * inv;
  ab[128 + c] = beta[c] - mean * inv * g;
}

// ---------------- fused norm+relu + out-GEMM: h = relu(pre*a+b); out (+)= h@Wp (+bp) ----------------
template<bool FIRST>
__global__ __launch_bounds__(256) void k_out(const float* __restrict__ pre, const float* __restrict__ ab,
                                             const float* __restrict__ Wp, const float* __restrict__ bp,
                                             float* __restrict__ h, float* __restrict__ out, int M) {
  __shared__ float At[D][TM];   // 32KB
  __shared__ float Ws[D][OUTC]; // 32KB
  int row0 = blockIdx.x * TM;
  int tid = threadIdx.x;
  // A tile: apply BN affine + relu while staging; also write h
  {
    int r = tid >> 2;
    int row = row0 + r;
    bool valid = (row < M);
    const float* Pp = pre + (size_t)row * D;
    float* Hp = h + (size_t)row * D;
    #pragma unroll
    for (int j = 0; j < 8; ++j) {
      int k4 = (tid & 3) + j * 4;
      int k = k4 * 4;
      float4 p = valid ? *(const float4*)(Pp + k) : make_float4(0.f, 0.f, 0.f, 0.f);
      float4 a = *(const float4*)(ab + k);
      float4 b = *(const float4*)(ab + 128 + k);
      float4 hv;
      hv.x = fmaxf(p.x * a.x + b.x, 0.f);
      hv.y = fmaxf(p.y * a.y + b.y, 0.f);
      hv.z = fmaxf(p.z * a.z + b.z, 0.f);
      hv.w = fmaxf(p.w * a.w + b.w, 0.f);
      if (valid) *(float4*)(Hp + k) = hv;
      At[k][r] = hv.x; At[k + 1][r] = hv.y; At[k + 2][r] = hv.z; At[k + 3][r] = hv.w;
    }
  }
  // Wp tile (128 x 64)
  {
    #pragma unroll
    for (int j = 0; j < 8; ++j) {
      int k = (tid >> 4) + j * 16;
      int c = (tid & 15) * 4;
      *(float4*)&Ws[k][c] = *(const float4*)(Wp + (size_t)k * OUTC + c);
    }
  }
  __syncthreads();

  int tx = tid & 15, ty = tid >> 4;
  float acc[4][4] = {};
  #pragma unroll 8
  for (int k = 0; k < D; ++k) {
    float4 a = *(const float4*)&At[k][ty * 4];
    float4 w = *(const float4*)&Ws[k][tx * 4];
    float av[4] = {a.x, a.y, a.z, a.w};
    float wv[4] = {w.x, w.y, w.z, w.w};
    #pragma unroll
    for (int r = 0; r < 4; ++r)
      #pragma unroll
      for (int c = 0; c < 4; ++c)
        acc[r][c] += av[r] * wv[c];
  }

  float4 bv = make_float4(0.f, 0.f, 0.f, 0.f);
  if (FIRST) bv = *(const float4*)&bp[tx * 4];
  #pragma unroll
  for (int r = 0; r < 4; ++r) {
    int row = row0 + ty * 4 + r;
    if (row < M) {
      float4* cp = (float4*)&out[(size_t)row * OUTC + tx * 4];
      float4 o;
      o.x = acc[r][0] + bv.x; o.y = acc[r][1] + bv.y;
      o.z = acc[r][2] + bv.z; o.w = acc[r][3] + bv.w;
      if (!FIRST) { float4 old = *cp; o.x += old.x; o.y += old.y; o.z += old.z; o.w += old.w; }
      *cp = o;
    }
  }
}

extern "C" void kernel_launch(void* const* d_in, const int* in_sizes, int n_in,
                              void* d_out, int out_size, void* d_ws, size_t ws_size,
                              hipStream_t stream) {
  const float* x     = (const float*)d_in[0];
  const int*   ei    = (const int*)d_in[1];
  const float* Wg    = (const float*)d_in[2];
  const float* bg    = (const float*)d_in[3];
  const float* Wl    = (const float*)d_in[4];
  const float* bl    = (const float*)d_in[5];
  const float* gamma = (const float*)d_in[6];
  const float* beta  = (const float*)d_in[7];
  const float* Wp    = (const float*)d_in[8];
  const float* bp    = (const float*)d_in[9];
  float* out = (float*)d_out;

  int N = in_sizes[0] / D;
  int E = in_sizes[1] / 2;
  const int* srcp = ei;
  const int* dstp = ei + E;

  char* wsb = (char*)d_ws;
  size_t off = 0;
  auto alloc = [&](size_t bytes) {
    off = (off + 255) & ~(size_t)255;
    void* p = wsb + off;
    off += bytes;
    return p;
  };
  float* dinv     = (float*)alloc((size_t)N * 4);
  int*   cnt      = (int*)alloc((size_t)N * 4);
  int*   rowstart = (int*)alloc((size_t)(N + 1) * 4);
  int*   cursor   = (int*)alloc((size_t)N * 4);
  int*   csr      = (int*)alloc((size_t)E * 4);
  int*   bsum     = (int*)alloc(1024 * 4);
  float* stats    = (float*)alloc(3 * 256 * 4);
  float* ab       = (float*)alloc(3 * 256 * 4);
  unsigned short* hg = (unsigned short*)alloc((size_t)N * D * 2);
  float* hl       = (float*)alloc((size_t)N * D * 4);
  float* h        = (float*)alloc((size_t)N * D * 4);
  (void)ws_size; (void)n_in; (void)out_size;

  hipMemsetAsync(cnt, 0, (size_t)N * 4, stream);
  hipMemsetAsync(stats, 0, 3 * 256 * 4, stream);

  int NB = (N + 1023) >> 10;
  k_count<<<512, 256, 0, stream>>>(dstp, cnt, E);
  k_scan1<<<NB, 256, 0, stream>>>(cnt, rowstart, bsum, N);
  k_scan2<<<1, 256, 0, stream>>>(bsum, NB);
  k_scan3<<<(N + 255) / 256, 256, 0, stream>>>(rowstart, bsum, cursor, cnt, dinv, N, E);
  k_fill<<<512, 256, 0, stream>>>(srcp, dstp, cursor, csr, E);

  int mt = (N + TM - 1) / TM;
  for (int i = 0; i < 3; ++i) {
    const float* A = (i == 0) ? x : h;
    k_dual<<<dim3(mt, 2), 256, 0, stream>>>(A, Wg + (size_t)i * D * D, Wl + (size_t)i * D * D, hg, hl, N);
    k_agg<<<(N + 3) / 4, 256, 0, stream>>>(hg, hl, rowstart, csr, dinv, bg + (size_t)i * D, bl + (size_t)i * D, N);
    k_stats<<<(N + 511) / 512, 256, 0, stream>>>(hl, stats + i * 256, N);
    k_finalize<<<1, 128, 0, stream>>>(stats + i * 256, gamma + (size_t)i * D, beta + (size_t)i * D, ab + i * 256, 1.0f / (float)N);
    if (i == 0) k_out<true ><<<mt, 256, 0, stream>>>(hl, ab + i * 256, Wp, bp, h, out, N);
    else        k_out<false><<<mt, 256, 0, stream>>>(hl, ab + i * 256, Wp, bp, h, out, N);
  }
}